// Round 5
// baseline (117.614 us; speedup 1.0000x reference)
//
#include <hip/hip_runtime.h>
#include <hip/hip_bf16.h>

// Problem constants (fixed by setup_inputs)
#define NB    16
#define NC    1024
#define NF    4096
#define NFINE (NB*NF)     // 65536
#define CIN   256
#define CSKIP 128
#define KH    (CIN+CSKIP) // 384
#define CMID  256
#define COUT  256

typedef __attribute__((ext_vector_type(8))) short short8;
typedef __attribute__((ext_vector_type(4))) float f32x4;
typedef __attribute__((ext_vector_type(4))) unsigned int u32x4;

// branchless sorted insert of (d, j) into (d0<=dA<=dB)
#define INS(d, j) do {                                        \
    bool c2 = (d) < dB, c1 = (d) < dA, c0 = (d) < d0;         \
    dB = c1 ? dA : (c2 ? (d) : dB);                           \
    iB = c1 ? iA : (c2 ? (j) : iB);                           \
    dA = c0 ? d0 : (c1 ? (d) : dA);                           \
    iA = c0 ? i0 : (c1 ? (j) : iA);                           \
    d0 = c0 ? (d) : d0;                                       \
    i0 = c0 ? (j) : i0;                                       \
} while (0)

// ---------------- K0: bin coarse points into 8^3 grid (counting sort) ----------------
__global__ __launch_bounds__(256)
void bin_kernel(const float* __restrict__ pos,
                float* __restrict__ gx, float* __restrict__ gy, float* __restrict__ gz,
                short* __restrict__ gsi, int* __restrict__ gcs)   // gcs: [NB][513]
{
    __shared__ int cnt[512];
    __shared__ float lx[NC], ly[NC], lz[NC];
    __shared__ short lcell[NC];
    const int b = blockIdx.x, t = threadIdx.x;
    for (int i = t; i < 512; i += 256) cnt[i] = 0;
    __syncthreads();
    const float* pc = pos + (size_t)b*NC*3;
    #pragma unroll
    for (int u = 0; u < 4; ++u) {
        int i = t + u*256;
        float x = pc[3*i+0], y = pc[3*i+1], z = pc[3*i+2];
        int cx = min(7, (int)(x*8.0f));
        int cy = min(7, (int)(y*8.0f));
        int cz = min(7, (int)(z*8.0f));
        int c = (cz*8 + cy)*8 + cx;
        lx[i] = x; ly[i] = y; lz[i] = z; lcell[i] = (short)c;
        atomicAdd(&cnt[c], 1);
    }
    __syncthreads();
    // exclusive prefix sum over 512 cells, wave 0 (lane L owns cells 8L..8L+7)
    if (t < 64) {
        int v[8]; int s = 0;
        #pragma unroll
        for (int u = 0; u < 8; ++u) { v[u] = cnt[t*8+u]; s += v[u]; }
        int pfx = s;
        #pragma unroll
        for (int m = 1; m < 64; m <<= 1) {
            int o = __shfl_up(pfx, m);
            if (t >= m) pfx += o;
        }
        pfx -= s;  // exclusive
        #pragma unroll
        for (int u = 0; u < 8; ++u) {
            gcs[b*513 + t*8+u] = pfx;
            cnt[t*8+u] = pfx;      // running scatter offset
            pfx += v[u];
        }
        if (t == 63) gcs[b*513 + 512] = NC;
    }
    __syncthreads();
    #pragma unroll
    for (int u = 0; u < 4; ++u) {
        int i = t + u*256;
        int c = lcell[i];
        int dst = atomicAdd(&cnt[c], 1);
        gx[b*NC+dst] = lx[i]; gy[b*NC+dst] = ly[i]; gz[b*NC+dst] = lz[i];
        gsi[b*NC+dst] = (short)i;
    }
}

// ---------------- K1: exact 3-NN via grid (ring-1 + guaranteed expansion) ----------------
__global__ __launch_bounds__(256)
void knn_grid_kernel(const float* __restrict__ pos_skip,
                     const float* __restrict__ gx, const float* __restrict__ gy,
                     const float* __restrict__ gz, const short* __restrict__ gsi,
                     const int* __restrict__ gcs,
                     int* __restrict__ widx, float* __restrict__ wval)
{
    __shared__ float px[NC], py[NC], pz[NC];
    __shared__ short si[NC];
    __shared__ int cs[513];
    const int b  = blockIdx.x >> 4;      // 16 blocks per cloud
    const int qb = blockIdx.x & 15;
    const int t  = threadIdx.x;
    for (int i = t; i < NC; i += 256) {
        px[i] = gx[b*NC+i]; py[i] = gy[b*NC+i]; pz[i] = gz[b*NC+i]; si[i] = gsi[b*NC+i];
    }
    for (int i = t; i < 513; i += 256) cs[i] = gcs[b*513+i];
    __syncthreads();

    const int q = b*NF + qb*256 + t;
    const float qx = pos_skip[(size_t)q*3+0];
    const float qy = pos_skip[(size_t)q*3+1];
    const float qz = pos_skip[(size_t)q*3+2];
    const int cx = min(7, (int)(qx*8.0f));
    const int cy = min(7, (int)(qy*8.0f));
    const int cz = min(7, (int)(qz*8.0f));

    float d0 = 3.0e38f, dA = 3.0e38f, dB = 3.0e38f;
    int   i0 = 0,       iA = 0,       iB = 0;

    // ---- ring 1: 3x3x3 clamped, x-cells fused into one contiguous span ----
    const int xlo = max(cx-1,0), xhi = min(cx+1,7);
    const int ylo = max(cy-1,0), yhi = min(cy+1,7);
    const int zlo = max(cz-1,0), zhi = min(cz+1,7);
    for (int z = zlo; z <= zhi; ++z)
    for (int y = ylo; y <= yhi; ++y) {
        const int rb = (z*8 + y)*8;
        int j  = cs[rb + xlo];
        const int je = cs[rb + xhi + 1];
        for (; j < je; ++j) {
            float fx = qx - px[j], fy = qy - py[j], fz = qz - pz[j];
            float d = fx*fx + fy*fy + fz*fz;
            INS(d, j);
        }
    }

    // ---- exactness margin: distance from q to scanned-box boundary (domain edges = INF) ----
    {
        float m = 3.0e38f;
        if (xlo > 0) m = fminf(m, qx - xlo*0.125f);
        if (xhi < 7) m = fminf(m, (xhi+1)*0.125f - qx);
        if (ylo > 0) m = fminf(m, qy - ylo*0.125f);
        if (yhi < 7) m = fminf(m, (yhi+1)*0.125f - qy);
        if (zlo > 0) m = fminf(m, qz - zlo*0.125f);
        if (zhi < 7) m = fminf(m, (zhi+1)*0.125f - qz);
        if (dB > m*m) {
            // ---- ring 2: 5x5x5 minus already-scanned 3x3x3 ----
            const int xlo2 = max(cx-2,0), xhi2 = min(cx+2,7);
            const int ylo2 = max(cy-2,0), yhi2 = min(cy+2,7);
            const int zlo2 = max(cz-2,0), zhi2 = min(cz+2,7);
            for (int z = zlo2; z <= zhi2; ++z)
            for (int y = ylo2; y <= yhi2; ++y) {
                const int rb = (z*8 + y)*8;
                const bool inner_zy = (z >= zlo && z <= zhi && y >= ylo && y <= yhi);
                if (inner_zy) {
                    // left edge cells [xlo2, xlo) and right edge (xhi, xhi2]
                    int j = cs[rb + xlo2]; const int je = cs[rb + xlo];
                    for (; j < je; ++j) {
                        float fx = qx - px[j], fy = qy - py[j], fz = qz - pz[j];
                        float d = fx*fx + fy*fy + fz*fz;
                        INS(d, j);
                    }
                    int j2 = cs[rb + xhi + 1]; const int je2 = cs[rb + xhi2 + 1];
                    for (; j2 < je2; ++j2) {
                        float fx = qx - px[j2], fy = qy - py[j2], fz = qz - pz[j2];
                        float d = fx*fx + fy*fy + fz*fz;
                        INS(d, j2);
                    }
                } else {
                    int j = cs[rb + xlo2]; const int je = cs[rb + xhi2 + 1];
                    for (; j < je; ++j) {
                        float fx = qx - px[j], fy = qy - py[j], fz = qz - pz[j];
                        float d = fx*fx + fy*fy + fz*fz;
                        INS(d, j);
                    }
                }
            }
            // margin of the 5x5x5 box; astronomically unlikely to fail, but stay exact
            float m2 = 3.0e38f;
            if (xlo2 > 0) m2 = fminf(m2, qx - xlo2*0.125f);
            if (xhi2 < 7) m2 = fminf(m2, (xhi2+1)*0.125f - qx);
            if (ylo2 > 0) m2 = fminf(m2, qy - ylo2*0.125f);
            if (yhi2 < 7) m2 = fminf(m2, (yhi2+1)*0.125f - qy);
            if (zlo2 > 0) m2 = fminf(m2, qz - zlo2*0.125f);
            if (zhi2 < 7) m2 = fminf(m2, (zhi2+1)*0.125f - qz);
            if (dB > m2*m2) {
                // full scan, skipping points whose cell lies inside the scanned 5x5x5 box
                for (int j = 0; j < NC; ++j) {
                    int pcx = min(7, (int)(px[j]*8.0f));
                    int pcy = min(7, (int)(py[j]*8.0f));
                    int pcz = min(7, (int)(pz[j]*8.0f));
                    if (pcx >= xlo2 && pcx <= xhi2 && pcy >= ylo2 && pcy <= yhi2 &&
                        pcz >= zlo2 && pcz <= zhi2) continue;
                    float fx = qx - px[j], fy = qy - py[j], fz = qz - pz[j];
                    float d = fx*fx + fy*fy + fz*fz;
                    INS(d, j);
                }
            }
        }
    }

    float w0 = 1.0f / fmaxf(d0, 1e-16f);
    float w1 = 1.0f / fmaxf(dA, 1e-16f);
    float w2 = 1.0f / fmaxf(dB, 1e-16f);
    float inv = 1.0f / (w0 + w1 + w2);
    widx[q*3+0] = b*NC + si[i0];  wval[q*3+0] = w0*inv;
    widx[q*3+1] = b*NC + si[iA];  wval[q*3+1] = w1*inv;
    widx[q*3+2] = b*NC + si[iB];  wval[q*3+2] = w2*inv;
}

// ---------------- K2: weights -> bf16, transposed [N][K] ----------------
__global__ __launch_bounds__(256)
void prep_weights(const float* __restrict__ W1, const float* __restrict__ W2,
                  __hip_bfloat16* __restrict__ W1t, __hip_bfloat16* __restrict__ W2t)
{
    int e = blockIdx.x*256 + threadIdx.x;
    if (e < CMID*KH) {
        int n = e / KH, k = e % KH;
        W1t[e] = __float2bfloat16(W1[(size_t)k*CMID + n]);
    }
    int e2 = e - CMID*KH;
    if (e2 >= 0 && e2 < COUT*CMID) {
        int n = e2 / CMID, k = e2 % CMID;
        W2t[e2] = __float2bfloat16(W2[(size_t)k*COUT + n]);
    }
}

// ---------------- fused GEMM: tile 128x256, 8 waves of 64x64, BK=64 ----------------
#define BMm  128
#define BNn  256
#define BKk  64

template<int MODE, int KTOT>   // MODE1: A = interp(x)|x_skip (fp32 sources); MODE0: A = bf16
__global__ __launch_bounds__(512, 2)
void gemm_fused(const void* __restrict__ Asrc,
                const float* __restrict__ x_skip,
                const int* __restrict__ widx,
                const float* __restrict__ wval,
                const __hip_bfloat16* __restrict__ Bt,   // [BNn][KTOT]
                const float* __restrict__ bias,
                __hip_bfloat16* __restrict__ outb,
                float* __restrict__ outf)
{
    __shared__ __align__(16) short As[BMm][BKk];
    __shared__ __align__(16) short Bs[BNn][BKk];
    constexpr int NSTEP = KTOT / BKk;

    const int nwg = gridDim.x;
    const int tile = (blockIdx.x & 7) * (nwg >> 3) + (blockIdx.x >> 3);
    const int m0 = tile * BMm;

    const int t = threadIdx.x;
    const int wave = t >> 6, lane = t & 63;
    const int wm = wave >> 2, wn = wave & 3;
    const int rl = lane & 15, kq = lane >> 4;
    const short* Br = (const short*)Bt;

    const int ar  = t >> 2;
    const int acb = t & 3;

    int j0=0, j1=0, j2=0; float w0=0.f, w1=0.f, w2=0.f;
    if (MODE == 1) {
        const int gr = m0 + ar;
        j0 = widx[gr*3+0]; j1 = widx[gr*3+1]; j2 = widx[gr*3+2];
        w0 = wval[gr*3+0]; w1 = wval[gr*3+1]; w2 = wval[gr*3+2];
    }

    f32x4 rA[12];
    u32x4 rB[4];

    #define LOADB(K0) do {                                                     \
        _Pragma("unroll")                                                      \
        for (int i = 0; i < 4; ++i) {                                          \
            const int ch = t + i*512;                                          \
            const int rr = ch >> 3, cc = ch & 7;                               \
            rB[i] = *(const u32x4*)&Br[(size_t)rr*KTOT + (K0) + cc*8];         \
        }                                                                      \
    } while (0)

    #define LOADA(K0) do {                                                     \
        if (MODE == 0) {                                                       \
            const short* Ar = (const short*)Asrc;                              \
            const short* p = &Ar[(size_t)(m0+ar)*KTOT + (K0) + acb*8];         \
            rA[0] = *(const f32x4*)p;                                          \
            rA[1] = *(const f32x4*)(p+32);                                     \
        } else if ((K0) < CIN) {                                               \
            const float* xp = (const float*)Asrc;                              \
            _Pragma("unroll")                                                  \
            for (int h = 0; h < 2; ++h) {                                      \
                const int k = (K0) + acb*8 + h*32;                             \
                const float* p0 = &xp[(size_t)j0*CIN + k];                     \
                const float* p1 = &xp[(size_t)j1*CIN + k];                     \
                const float* p2 = &xp[(size_t)j2*CIN + k];                     \
                rA[h*6+0] = *(const f32x4*)p0; rA[h*6+1] = *(const f32x4*)(p0+4); \
                rA[h*6+2] = *(const f32x4*)p1; rA[h*6+3] = *(const f32x4*)(p1+4); \
                rA[h*6+4] = *(const f32x4*)p2; rA[h*6+5] = *(const f32x4*)(p2+4); \
            }                                                                  \
        } else {                                                               \
            _Pragma("unroll")                                                  \
            for (int h = 0; h < 2; ++h) {                                      \
                const int k = (K0) + acb*8 + h*32 - CIN;                       \
                const float* sp = &x_skip[(size_t)(m0+ar)*CSKIP + k];          \
                rA[h*2+0] = *(const f32x4*)sp; rA[h*2+1] = *(const f32x4*)(sp+4); \
            }                                                                  \
        }                                                                      \
    } while (0)

    f32x4 acc[4][4] = {};

    LOADA(0); LOADB(0);

    #pragma unroll
    for (int s = 0; s < NSTEP; ++s) {
        const int k0 = s * BKk;
        __syncthreads();
        if (MODE == 0) {
            *(u32x4*)&As[ar][((acb  ) ^ (ar&7))*8] = *(u32x4*)&rA[0];
            *(u32x4*)&As[ar][((acb+4) ^ (ar&7))*8] = *(u32x4*)&rA[1];
        } else if (k0 < CIN) {
            #pragma unroll
            for (int h = 0; h < 2; ++h) {
                short8 sv;
                #pragma unroll
                for (int u = 0; u < 2; ++u) {
                    f32x4 a = rA[h*6+u], bq = rA[h*6+2+u], c = rA[h*6+4+u];
                    #pragma unroll
                    for (int e = 0; e < 4; ++e) {
                        float v = w0*a[e] + w1*bq[e] + w2*c[e];
                        __hip_bfloat16 bb = __float2bfloat16(v);
                        ((short*)&sv)[u*4+e] = *(short*)&bb;
                    }
                }
                *(short8*)&As[ar][((acb + h*4) ^ (ar&7))*8] = sv;
            }
        } else {
            #pragma unroll
            for (int h = 0; h < 2; ++h) {
                short8 sv;
                #pragma unroll
                for (int u = 0; u < 2; ++u) {
                    f32x4 a = rA[h*2+u];
                    #pragma unroll
                    for (int e = 0; e < 4; ++e) {
                        __hip_bfloat16 bb = __float2bfloat16(a[e]);
                        ((short*)&sv)[u*4+e] = *(short*)&bb;
                    }
                }
                *(short8*)&As[ar][((acb + h*4) ^ (ar&7))*8] = sv;
            }
        }
        #pragma unroll
        for (int i = 0; i < 4; ++i) {
            const int ch = t + i*512;
            const int rr = ch >> 3, cc = ch & 7;
            *(u32x4*)&Bs[rr][(cc ^ (rr&7))*8] = rB[i];
        }
        __syncthreads();
        if (s + 1 < NSTEP) { LOADA(k0 + BKk); LOADB(k0 + BKk); }
        #pragma unroll
        for (int kh = 0; kh < 2; ++kh) {
            const int kc = kh*4 + kq;
            short8 af[4], bf[4];
            #pragma unroll
            for (int mf = 0; mf < 4; ++mf)
                af[mf] = *(const short8*)&As[wm*64 + mf*16 + rl][(kc ^ (rl&7))*8];
            #pragma unroll
            for (int nf = 0; nf < 4; ++nf)
                bf[nf] = *(const short8*)&Bs[wn*64 + nf*16 + rl][(kc ^ (rl&7))*8];
            #pragma unroll
            for (int mf = 0; mf < 4; ++mf)
            #pragma unroll
            for (int nf = 0; nf < 4; ++nf)
                acc[mf][nf] = __builtin_amdgcn_mfma_f32_16x16x32_bf16(af[mf], bf[nf], acc[mf][nf], 0,0,0);
        }
    }
    #undef LOADA
    #undef LOADB

    #pragma unroll
    for (int mf = 0; mf < 4; ++mf)
    #pragma unroll
    for (int nf = 0; nf < 4; ++nf) {
        const int col = wn*64 + nf*16 + rl;
        const float bv = bias[col];
        #pragma unroll
        for (int i = 0; i < 4; ++i) {
            const int row = m0 + wm*64 + mf*16 + kq*4 + i;
            float v = fmaxf(acc[mf][nf][i] + bv, 0.0f);
            if (MODE == 1) outb[(size_t)row*BNn + col] = __float2bfloat16(v);
            else           outf[(size_t)row*BNn + col] = v;
        }
    }
}

// ---------------- K6: pos_skip + batch chunks ----------------
__global__ __launch_bounds__(256)
void tail_kernel(const float* __restrict__ pos_skip, float* __restrict__ out)
{
    int e = blockIdx.x*256 + threadIdx.x;
    if (e < NFINE*3) out[(size_t)NFINE*COUT + e] = pos_skip[e];
    if (e < NFINE)   out[(size_t)NFINE*COUT + (size_t)NFINE*3 + e] = (float)(e / NF);
}

extern "C" void kernel_launch(void* const* d_in, const int* in_sizes, int n_in,
                              void* d_out, int out_size, void* d_ws, size_t ws_size,
                              hipStream_t stream) {
    const float* x        = (const float*)d_in[0];
    const float* pos      = (const float*)d_in[1];
    const float* x_skip   = (const float*)d_in[4];
    const float* pos_skip = (const float*)d_in[5];
    const float* W1       = (const float*)d_in[8];
    const float* b1       = (const float*)d_in[9];
    const float* W2       = (const float*)d_in[10];
    const float* b2       = (const float*)d_in[11];
    float* out = (float*)d_out;
    char* ws = (char*)d_ws;

    int*            widx = (int*)  (ws + 0);                 //   786,432 B
    float*          wval = (float*)(ws + 786432);            //   786,432 B
    __hip_bfloat16* W1t  = (__hip_bfloat16*)(ws + 1572864);  //   196,608 B
    __hip_bfloat16* W2t  = (__hip_bfloat16*)(ws + 1769472);  //   131,072 B
    __hip_bfloat16* h1   = (__hip_bfloat16*)(ws + 1900544);  // 33,554,432 B
    float*          gx   = (float*)(ws + 35454976);          //    65,536 B
    float*          gy   = (float*)(ws + 35520512);
    float*          gz   = (float*)(ws + 35586048);
    short*          gsi  = (short*)(ws + 35651584);          //    32,768 B
    int*            gcs  = (int*)  (ws + 35684352);          //    32,832 B

    hipLaunchKernelGGL(bin_kernel, dim3(NB), dim3(256), 0, stream,
                       pos, gx, gy, gz, gsi, gcs);
    hipLaunchKernelGGL(knn_grid_kernel, dim3(NFINE/256), dim3(256), 0, stream,
                       pos_skip, gx, gy, gz, gsi, gcs, widx, wval);
    hipLaunchKernelGGL(prep_weights, dim3((CMID*KH + COUT*CMID + 255)/256), dim3(256), 0, stream,
                       W1, W2, W1t, W2t);
    hipLaunchKernelGGL((gemm_fused<1, KH>), dim3(NFINE/BMm), dim3(512), 0, stream,
                       x, x_skip, widx, wval, W1t, b1, h1, nullptr);
    hipLaunchKernelGGL((gemm_fused<0, CMID>), dim3(NFINE/BMm), dim3(512), 0, stream,
                       h1, nullptr, nullptr, nullptr, W2t, b2, nullptr, out);
    hipLaunchKernelGGL(tail_kernel, dim3((NFINE*3 + 255)/256), dim3(256), 0, stream,
                       pos_skip, out);
}

// Round 6
// 87.681 us; speedup vs baseline: 1.3414x; 1.3414x over previous
//
#include <hip/hip_runtime.h>
#include <hip/hip_bf16.h>

// Problem constants (fixed by setup_inputs)
#define NB    16
#define NC    1024
#define NF    4096
#define NFINE (NB*NF)     // 65536
#define CIN   256
#define CSKIP 128
#define KH    (CIN+CSKIP) // 384
#define CMID  256
#define COUT  256

typedef __attribute__((ext_vector_type(8))) short short8;
typedef __attribute__((ext_vector_type(4))) float f32x4;
typedef __attribute__((ext_vector_type(4))) unsigned int u32x4;

// branchless sorted insert of (d, j) into (d0<=dA<=dB)
#define INS(d, j) do {                                        \
    bool c2 = (d) < dB, c1 = (d) < dA, c0 = (d) < d0;         \
    dB = c1 ? dA : (c2 ? (d) : dB);                           \
    iB = c1 ? iA : (c2 ? (j) : iB);                           \
    dA = c0 ? d0 : (c1 ? (d) : dA);                           \
    iA = c0 ? i0 : (c1 ? (j) : iA);                           \
    d0 = c0 ? (d) : d0;                                       \
    i0 = c0 ? (j) : i0;                                       \
} while (0)

// merge sorted triples across the 8-lane group (lanes consecutive)
#define MERGE8() do {                                                          \
    _Pragma("unroll")                                                          \
    for (int m = 1; m < 8; m <<= 1) {                                          \
        float e0 = __shfl_xor(d0, m), e1 = __shfl_xor(dA, m), e2 = __shfl_xor(dB, m); \
        int   f0 = __shfl_xor(i0, m), f1 = __shfl_xor(iA, m), f2 = __shfl_xor(iB, m); \
        INS(e0, f0); INS(e1, f1); INS(e2, f2);                                 \
    }                                                                          \
} while (0)

// ---------------- K0: bin coarse points into 8^3 grid (counting sort) ----------------
__global__ __launch_bounds__(256)
void bin_kernel(const float* __restrict__ pos,
                float* __restrict__ gx, float* __restrict__ gy, float* __restrict__ gz,
                short* __restrict__ gsi, int* __restrict__ gcs)   // gcs: [NB][513]
{
    __shared__ int cnt[512];
    __shared__ float lx[NC], ly[NC], lz[NC];
    __shared__ short lcell[NC];
    const int b = blockIdx.x, t = threadIdx.x;
    for (int i = t; i < 512; i += 256) cnt[i] = 0;
    __syncthreads();
    const float* pc = pos + (size_t)b*NC*3;
    #pragma unroll
    for (int u = 0; u < 4; ++u) {
        int i = t + u*256;
        float x = pc[3*i+0], y = pc[3*i+1], z = pc[3*i+2];
        int cx = min(7, (int)(x*8.0f));
        int cy = min(7, (int)(y*8.0f));
        int cz = min(7, (int)(z*8.0f));
        int c = (cz*8 + cy)*8 + cx;
        lx[i] = x; ly[i] = y; lz[i] = z; lcell[i] = (short)c;
        atomicAdd(&cnt[c], 1);
    }
    __syncthreads();
    if (t < 64) {
        int v[8]; int s = 0;
        #pragma unroll
        for (int u = 0; u < 8; ++u) { v[u] = cnt[t*8+u]; s += v[u]; }
        int pfx = s;
        #pragma unroll
        for (int m = 1; m < 64; m <<= 1) {
            int o = __shfl_up(pfx, m);
            if (t >= m) pfx += o;
        }
        pfx -= s;  // exclusive
        #pragma unroll
        for (int u = 0; u < 8; ++u) {
            gcs[b*513 + t*8+u] = pfx;
            cnt[t*8+u] = pfx;
            pfx += v[u];
        }
        if (t == 63) gcs[b*513 + 512] = NC;
    }
    __syncthreads();
    #pragma unroll
    for (int u = 0; u < 4; ++u) {
        int i = t + u*256;
        int c = lcell[i];
        int dst = atomicAdd(&cnt[c], 1);
        gx[b*NC+dst] = lx[i]; gy[b*NC+dst] = ly[i]; gz[b*NC+dst] = lz[i];
        gsi[b*NC+dst] = (short)i;
    }
}

// ---------------- K1: exact 3-NN via grid, 8 lanes per query ----------------
#define KQPB 32   // queries per 256-thread block -> 2048 blocks, 8/CU

__global__ __launch_bounds__(256)
void knn_grid_kernel(const float* __restrict__ pos_skip,
                     const float* __restrict__ gx, const float* __restrict__ gy,
                     const float* __restrict__ gz, const short* __restrict__ gsi,
                     const int* __restrict__ gcs,
                     int* __restrict__ widx, float* __restrict__ wval)
{
    __shared__ float px[NC], py[NC], pz[NC];
    __shared__ short si[NC];
    __shared__ int cs[513];
    const int bpc = NF/KQPB;              // 128 blocks per cloud
    const int b  = blockIdx.x / bpc;
    const int qb = blockIdx.x % bpc;
    const int t  = threadIdx.x;
    for (int i = t; i < NC; i += 256) {
        px[i] = gx[b*NC+i]; py[i] = gy[b*NC+i]; pz[i] = gz[b*NC+i]; si[i] = gsi[b*NC+i];
    }
    for (int i = t; i < 513; i += 256) cs[i] = gcs[b*513+i];
    __syncthreads();

    const int g  = t & 7;                 // lane within 8-lane group
    const int ql = t >> 3;                // query slot (0..31)
    const int q  = b*NF + qb*KQPB + ql;
    const float qx = pos_skip[(size_t)q*3+0];
    const float qy = pos_skip[(size_t)q*3+1];
    const float qz = pos_skip[(size_t)q*3+2];
    const int cx = min(7, (int)(qx*8.0f));
    const int cy = min(7, (int)(qy*8.0f));
    const int cz = min(7, (int)(qz*8.0f));

    float d0 = 3.0e38f, dA = 3.0e38f, dB = 3.0e38f;
    int   i0 = 0,       iA = 0,       iB = 0;

    // ---- ring 1: 3x3x3 clamped; 9 uniform (z,y) rows, x-span fused; lanes stride by 8 ----
    const int xlo = max(cx-1,0), xhi = min(cx+1,7);
    const int ylo = max(cy-1,0), yhi = min(cy+1,7);
    const int zlo = max(cz-1,0), zhi = min(cz+1,7);
    #pragma unroll
    for (int r = 0; r < 9; ++r) {
        const int z = cz - 1 + r/3;
        const int y = cy - 1 + r%3;
        const bool ok = ((unsigned)z < 8u) & ((unsigned)y < 8u);
        const int rb = (z*8 + y)*8;
        int js = 0, je = 0;
        if (ok) { js = cs[rb + xlo]; je = cs[rb + xhi + 1]; }
        for (int j = js + g; j < je; j += 8) {
            float fx = qx - px[j], fy = qy - py[j], fz = qz - pz[j];
            float d = fx*fx + fy*fy + fz*fz;
            INS(d, j);
        }
    }
    MERGE8();   // all 8 lanes now hold the identical ring-1 top-3

    // ---- exactness margin of the scanned box (domain edges contribute INF) ----
    float m1 = 3.0e38f;
    if (xlo > 0) m1 = fminf(m1, qx - xlo*0.125f);
    if (xhi < 7) m1 = fminf(m1, (xhi+1)*0.125f - qx);
    if (ylo > 0) m1 = fminf(m1, qy - ylo*0.125f);
    if (yhi < 7) m1 = fminf(m1, (yhi+1)*0.125f - qy);
    if (zlo > 0) m1 = fminf(m1, qz - zlo*0.125f);
    if (zhi < 7) m1 = fminf(m1, (zhi+1)*0.125f - qz);

    if (dB > m1*m1) {   // group-uniform branch (prob ~1-2%)
        // save ring-1 result; rescan DISJOINT cells only (no duplicate indices)
        const float s0 = d0, s1 = dA, s2 = dB;
        const int   t0 = i0, t1 = iA, t2 = iB;
        d0 = dA = dB = 3.0e38f; i0 = iA = iB = 0;

        const int xlo2 = max(cx-2,0), xhi2 = min(cx+2,7);
        const int ylo2 = max(cy-2,0), yhi2 = min(cy+2,7);
        const int zlo2 = max(cz-2,0), zhi2 = min(cz+2,7);
        for (int z = zlo2; z <= zhi2; ++z)
        for (int y = ylo2; y <= yhi2; ++y) {
            const int rb = (z*8 + y)*8;
            const bool inner_zy = (z >= zlo && z <= zhi && y >= ylo && y <= yhi);
            int jsA, jeA, jsB, jeB;
            if (inner_zy) {         // only the x-edges not already scanned
                jsA = cs[rb + xlo2]; jeA = cs[rb + xlo];
                jsB = cs[rb + xhi + 1]; jeB = cs[rb + xhi2 + 1];
            } else {                // whole row
                jsA = cs[rb + xlo2]; jeA = cs[rb + xhi2 + 1];
                jsB = 0; jeB = 0;
            }
            for (int j = jsA + g; j < jeA; j += 8) {
                float fx = qx - px[j], fy = qy - py[j], fz = qz - pz[j];
                float d = fx*fx + fy*fy + fz*fz;
                INS(d, j);
            }
            for (int j = jsB + g; j < jeB; j += 8) {
                float fx = qx - px[j], fy = qy - py[j], fz = qz - pz[j];
                float d = fx*fx + fy*fy + fz*fz;
                INS(d, j);
            }
        }
        MERGE8();
        INS(s0, t0); INS(s1, t1); INS(s2, t2);   // identical on all lanes

        float m2 = 3.0e38f;
        if (xlo2 > 0) m2 = fminf(m2, qx - xlo2*0.125f);
        if (xhi2 < 7) m2 = fminf(m2, (xhi2+1)*0.125f - qx);
        if (ylo2 > 0) m2 = fminf(m2, qy - ylo2*0.125f);
        if (yhi2 < 7) m2 = fminf(m2, (yhi2+1)*0.125f - qy);
        if (zlo2 > 0) m2 = fminf(m2, qz - zlo2*0.125f);
        if (zhi2 < 7) m2 = fminf(m2, (zhi2+1)*0.125f - qz);
        if (dB > m2*m2) {   // astronomically rare; keeps exactness
            const float u0 = d0, u1 = dA, u2 = dB;
            const int   v0 = i0, v1 = iA, v2 = iB;
            d0 = dA = dB = 3.0e38f; i0 = iA = iB = 0;
            for (int j = g; j < NC; j += 8) {
                int pcx = min(7, (int)(px[j]*8.0f));
                int pcy = min(7, (int)(py[j]*8.0f));
                int pcz = min(7, (int)(pz[j]*8.0f));
                if (pcx >= xlo2 && pcx <= xhi2 && pcy >= ylo2 && pcy <= yhi2 &&
                    pcz >= zlo2 && pcz <= zhi2) continue;   // already scanned
                float fx = qx - px[j], fy = qy - py[j], fz = qz - pz[j];
                float d = fx*fx + fy*fy + fz*fz;
                INS(d, j);
            }
            MERGE8();
            INS(u0, v0); INS(u1, v1); INS(u2, v2);
        }
    }

    if (g == 0) {
        float w0 = 1.0f / fmaxf(d0, 1e-16f);
        float w1 = 1.0f / fmaxf(dA, 1e-16f);
        float w2 = 1.0f / fmaxf(dB, 1e-16f);
        float inv = 1.0f / (w0 + w1 + w2);
        widx[q*3+0] = b*NC + si[i0];  wval[q*3+0] = w0*inv;
        widx[q*3+1] = b*NC + si[iA];  wval[q*3+1] = w1*inv;
        widx[q*3+2] = b*NC + si[iB];  wval[q*3+2] = w2*inv;
    }
}

// ---------------- K2: weights -> bf16, transposed [N][K] ----------------
__global__ __launch_bounds__(256)
void prep_weights(const float* __restrict__ W1, const float* __restrict__ W2,
                  __hip_bfloat16* __restrict__ W1t, __hip_bfloat16* __restrict__ W2t)
{
    int e = blockIdx.x*256 + threadIdx.x;
    if (e < CMID*KH) {
        int n = e / KH, k = e % KH;
        W1t[e] = __float2bfloat16(W1[(size_t)k*CMID + n]);
    }
    int e2 = e - CMID*KH;
    if (e2 >= 0 && e2 < COUT*CMID) {
        int n = e2 / CMID, k = e2 % CMID;
        W2t[e2] = __float2bfloat16(W2[(size_t)k*COUT + n]);
    }
}

// ---------------- fused GEMM: tile 128x256, 8 waves of 64x64, BK=64 ----------------
#define BMm  128
#define BNn  256
#define BKk  64

template<int MODE, int KTOT>   // MODE1: A = interp(x)|x_skip (fp32 sources); MODE0: A = bf16
__global__ __launch_bounds__(512, 2)
void gemm_fused(const void* __restrict__ Asrc,
                const float* __restrict__ x_skip,
                const int* __restrict__ widx,
                const float* __restrict__ wval,
                const __hip_bfloat16* __restrict__ Bt,   // [BNn][KTOT]
                const float* __restrict__ bias,
                __hip_bfloat16* __restrict__ outb,
                float* __restrict__ outf)
{
    __shared__ __align__(16) short As[BMm][BKk];
    __shared__ __align__(16) short Bs[BNn][BKk];
    constexpr int NSTEP = KTOT / BKk;

    const int nwg = gridDim.x;
    const int tile = (blockIdx.x & 7) * (nwg >> 3) + (blockIdx.x >> 3);
    const int m0 = tile * BMm;

    const int t = threadIdx.x;
    const int wave = t >> 6, lane = t & 63;
    const int wm = wave >> 2, wn = wave & 3;
    const int rl = lane & 15, kq = lane >> 4;
    const short* Br = (const short*)Bt;

    const int ar  = t >> 2;
    const int acb = t & 3;

    int j0=0, j1=0, j2=0; float w0=0.f, w1=0.f, w2=0.f;
    if (MODE == 1) {
        const int gr = m0 + ar;
        j0 = widx[gr*3+0]; j1 = widx[gr*3+1]; j2 = widx[gr*3+2];
        w0 = wval[gr*3+0]; w1 = wval[gr*3+1]; w2 = wval[gr*3+2];
    }

    f32x4 rA[12];
    u32x4 rB[4];

    #define LOADB(K0) do {                                                     \
        _Pragma("unroll")                                                      \
        for (int i = 0; i < 4; ++i) {                                          \
            const int ch = t + i*512;                                          \
            const int rr = ch >> 3, cc = ch & 7;                               \
            rB[i] = *(const u32x4*)&Br[(size_t)rr*KTOT + (K0) + cc*8];         \
        }                                                                      \
    } while (0)

    #define LOADA(K0) do {                                                     \
        if (MODE == 0) {                                                       \
            const short* Ar = (const short*)Asrc;                              \
            const short* p = &Ar[(size_t)(m0+ar)*KTOT + (K0) + acb*8];         \
            rA[0] = *(const f32x4*)p;                                          \
            rA[1] = *(const f32x4*)(p+32);                                     \
        } else if ((K0) < CIN) {                                               \
            const float* xp = (const float*)Asrc;                              \
            _Pragma("unroll")                                                  \
            for (int h = 0; h < 2; ++h) {                                      \
                const int k = (K0) + acb*8 + h*32;                             \
                const float* p0 = &xp[(size_t)j0*CIN + k];                     \
                const float* p1 = &xp[(size_t)j1*CIN + k];                     \
                const float* p2 = &xp[(size_t)j2*CIN + k];                     \
                rA[h*6+0] = *(const f32x4*)p0; rA[h*6+1] = *(const f32x4*)(p0+4); \
                rA[h*6+2] = *(const f32x4*)p1; rA[h*6+3] = *(const f32x4*)(p1+4); \
                rA[h*6+4] = *(const f32x4*)p2; rA[h*6+5] = *(const f32x4*)(p2+4); \
            }                                                                  \
        } else {                                                               \
            _Pragma("unroll")                                                  \
            for (int h = 0; h < 2; ++h) {                                      \
                const int k = (K0) + acb*8 + h*32 - CIN;                       \
                const float* sp = &x_skip[(size_t)(m0+ar)*CSKIP + k];          \
                rA[h*2+0] = *(const f32x4*)sp; rA[h*2+1] = *(const f32x4*)(sp+4); \
            }                                                                  \
        }                                                                      \
    } while (0)

    f32x4 acc[4][4] = {};

    LOADA(0); LOADB(0);

    #pragma unroll
    for (int s = 0; s < NSTEP; ++s) {
        const int k0 = s * BKk;
        __syncthreads();
        if (MODE == 0) {
            *(u32x4*)&As[ar][((acb  ) ^ (ar&7))*8] = *(u32x4*)&rA[0];
            *(u32x4*)&As[ar][((acb+4) ^ (ar&7))*8] = *(u32x4*)&rA[1];
        } else if (k0 < CIN) {
            #pragma unroll
            for (int h = 0; h < 2; ++h) {
                short8 sv;
                #pragma unroll
                for (int u = 0; u < 2; ++u) {
                    f32x4 a = rA[h*6+u], bq = rA[h*6+2+u], c = rA[h*6+4+u];
                    #pragma unroll
                    for (int e = 0; e < 4; ++e) {
                        float v = w0*a[e] + w1*bq[e] + w2*c[e];
                        __hip_bfloat16 bb = __float2bfloat16(v);
                        ((short*)&sv)[u*4+e] = *(short*)&bb;
                    }
                }
                *(short8*)&As[ar][((acb + h*4) ^ (ar&7))*8] = sv;
            }
        } else {
            #pragma unroll
            for (int h = 0; h < 2; ++h) {
                short8 sv;
                #pragma unroll
                for (int u = 0; u < 2; ++u) {
                    f32x4 a = rA[h*2+u];
                    #pragma unroll
                    for (int e = 0; e < 4; ++e) {
                        __hip_bfloat16 bb = __float2bfloat16(a[e]);
                        ((short*)&sv)[u*4+e] = *(short*)&bb;
                    }
                }
                *(short8*)&As[ar][((acb + h*4) ^ (ar&7))*8] = sv;
            }
        }
        #pragma unroll
        for (int i = 0; i < 4; ++i) {
            const int ch = t + i*512;
            const int rr = ch >> 3, cc = ch & 7;
            *(u32x4*)&Bs[rr][(cc ^ (rr&7))*8] = rB[i];
        }
        __syncthreads();
        if (s + 1 < NSTEP) { LOADA(k0 + BKk); LOADB(k0 + BKk); }
        #pragma unroll
        for (int kh = 0; kh < 2; ++kh) {
            const int kc = kh*4 + kq;
            short8 af[4], bf[4];
            #pragma unroll
            for (int mf = 0; mf < 4; ++mf)
                af[mf] = *(const short8*)&As[wm*64 + mf*16 + rl][(kc ^ (rl&7))*8];
            #pragma unroll
            for (int nf = 0; nf < 4; ++nf)
                bf[nf] = *(const short8*)&Bs[wn*64 + nf*16 + rl][(kc ^ (rl&7))*8];
            #pragma unroll
            for (int mf = 0; mf < 4; ++mf)
            #pragma unroll
            for (int nf = 0; nf < 4; ++nf)
                acc[mf][nf] = __builtin_amdgcn_mfma_f32_16x16x32_bf16(af[mf], bf[nf], acc[mf][nf], 0,0,0);
        }
    }
    #undef LOADA
    #undef LOADB

    #pragma unroll
    for (int mf = 0; mf < 4; ++mf)
    #pragma unroll
    for (int nf = 0; nf < 4; ++nf) {
        const int col = wn*64 + nf*16 + rl;
        const float bv = bias[col];
        #pragma unroll
        for (int i = 0; i < 4; ++i) {
            const int row = m0 + wm*64 + mf*16 + kq*4 + i;
            float v = fmaxf(acc[mf][nf][i] + bv, 0.0f);
            if (MODE == 1) outb[(size_t)row*BNn + col] = __float2bfloat16(v);
            else           outf[(size_t)row*BNn + col] = v;
        }
    }
}

// ---------------- K6: pos_skip + batch chunks ----------------
__global__ __launch_bounds__(256)
void tail_kernel(const float* __restrict__ pos_skip, float* __restrict__ out)
{
    int e = blockIdx.x*256 + threadIdx.x;
    if (e < NFINE*3) out[(size_t)NFINE*COUT + e] = pos_skip[e];
    if (e < NFINE)   out[(size_t)NFINE*COUT + (size_t)NFINE*3 + e] = (float)(e / NF);
}

extern "C" void kernel_launch(void* const* d_in, const int* in_sizes, int n_in,
                              void* d_out, int out_size, void* d_ws, size_t ws_size,
                              hipStream_t stream) {
    const float* x        = (const float*)d_in[0];
    const float* pos      = (const float*)d_in[1];
    const float* x_skip   = (const float*)d_in[4];
    const float* pos_skip = (const float*)d_in[5];
    const float* W1       = (const float*)d_in[8];
    const float* b1       = (const float*)d_in[9];
    const float* W2       = (const float*)d_in[10];
    const float* b2       = (const float*)d_in[11];
    float* out = (float*)d_out;
    char* ws = (char*)d_ws;

    int*            widx = (int*)  (ws + 0);                 //   786,432 B
    float*          wval = (float*)(ws + 786432);            //   786,432 B
    __hip_bfloat16* W1t  = (__hip_bfloat16*)(ws + 1572864);  //   196,608 B
    __hip_bfloat16* W2t  = (__hip_bfloat16*)(ws + 1769472);  //   131,072 B
    __hip_bfloat16* h1   = (__hip_bfloat16*)(ws + 1900544);  // 33,554,432 B
    float*          gx   = (float*)(ws + 35454976);
    float*          gy   = (float*)(ws + 35520512);
    float*          gz   = (float*)(ws + 35586048);
    short*          gsi  = (short*)(ws + 35651584);
    int*            gcs  = (int*)  (ws + 35684352);

    hipLaunchKernelGGL(bin_kernel, dim3(NB), dim3(256), 0, stream,
                       pos, gx, gy, gz, gsi, gcs);
    hipLaunchKernelGGL(knn_grid_kernel, dim3(NB*(NF/KQPB)), dim3(256), 0, stream,
                       pos_skip, gx, gy, gz, gsi, gcs, widx, wval);
    hipLaunchKernelGGL(prep_weights, dim3((CMID*KH + COUT*CMID + 255)/256), dim3(256), 0, stream,
                       W1, W2, W1t, W2t);
    hipLaunchKernelGGL((gemm_fused<1, KH>), dim3(NFINE/BMm), dim3(512), 0, stream,
                       x, x_skip, widx, wval, W1t, b1, h1, nullptr);
    hipLaunchKernelGGL((gemm_fused<0, CMID>), dim3(NFINE/BMm), dim3(512), 0, stream,
                       h1, nullptr, nullptr, nullptr, W2t, b2, nullptr, out);
    hipLaunchKernelGGL(tail_kernel, dim3((NFINE*3 + 255)/256), dim3(256), 0, stream,
                       pos_skip, out);
}

// Round 8
// 76.578 us; speedup vs baseline: 1.5359x; 1.1450x over previous
//
#include <hip/hip_runtime.h>
#include <hip/hip_bf16.h>

// Problem constants (fixed by setup_inputs)
#define NB    16
#define NC    1024
#define NF    4096
#define NFINE (NB*NF)     // 65536
#define CIN   256
#define CSKIP 128
#define KH    (CIN+CSKIP) // 384
#define CMID  256
#define COUT  256

typedef __attribute__((ext_vector_type(8))) short short8;
typedef __attribute__((ext_vector_type(4))) float f32x4;
typedef __attribute__((ext_vector_type(4))) unsigned int u32x4;

// ---------------- K0: bin coarse points into 8^3 grid (counting sort) ----------------
// Output: gp[i] = float4{x,y,z, idx_as_float}, gcs[b][513] cell starts.
__global__ __launch_bounds__(256)
void bin_kernel(const float* __restrict__ pos,
                float* __restrict__ gp,          // [NB*NC*4]
                int* __restrict__ gcs)           // [NB*513]
{
    __shared__ int cnt[512];
    __shared__ float lx[NC], ly[NC], lz[NC];
    __shared__ short lcell[NC];
    const int b = blockIdx.x, t = threadIdx.x;
    for (int i = t; i < 512; i += 256) cnt[i] = 0;
    __syncthreads();
    const float* pc = pos + (size_t)b*NC*3;
    #pragma unroll
    for (int u = 0; u < 4; ++u) {
        int i = t + u*256;
        float x = pc[3*i+0], y = pc[3*i+1], z = pc[3*i+2];
        int cx = min(7, (int)(x*8.0f));
        int cy = min(7, (int)(y*8.0f));
        int cz = min(7, (int)(z*8.0f));
        int c = (cz*8 + cy)*8 + cx;
        lx[i] = x; ly[i] = y; lz[i] = z; lcell[i] = (short)c;
        atomicAdd(&cnt[c], 1);
    }
    __syncthreads();
    if (t < 64) {   // exclusive prefix sum over 512 cells (lane owns 8)
        int v[8]; int s = 0;
        #pragma unroll
        for (int u = 0; u < 8; ++u) { v[u] = cnt[t*8+u]; s += v[u]; }
        int pfx = s;
        #pragma unroll
        for (int m = 1; m < 64; m <<= 1) {
            int o = __shfl_up(pfx, m);
            if (t >= m) pfx += o;
        }
        pfx -= s;
        #pragma unroll
        for (int u = 0; u < 8; ++u) {
            gcs[b*513 + t*8+u] = pfx;
            cnt[t*8+u] = pfx;
            pfx += v[u];
        }
        if (t == 63) gcs[b*513 + 512] = NC;
    }
    __syncthreads();
    #pragma unroll
    for (int u = 0; u < 4; ++u) {
        int i = t + u*256;
        int c = lcell[i];
        int dst = atomicAdd(&cnt[c], 1);
        f32x4 v; v[0] = lx[i]; v[1] = ly[i]; v[2] = lz[i]; v[3] = __int_as_float(i);
        *(f32x4*)&gp[(size_t)(b*NC + dst)*4] = v;
    }
}

// ---------------- K1: exact 3-NN via grid, 8 lanes/query ----------------
// EXACT selection: full-precision (d^2, j) pairs, branchless sorted insert.
// (r7's packed-key truncation swapped near-tie neighbors -> 0.43 absmax. Reverted.)
#define KQPB 32   // queries per 256-thread block -> 2048 blocks

// branchless sorted insert of (d, j) into (d0<=dA<=dB)
#define INS(d, j) do {                                        \
    bool c2 = (d) < dB, c1 = (d) < dA, c0 = (d) < d0;         \
    dB = c1 ? dA : (c2 ? (d) : dB);                           \
    iB = c1 ? iA : (c2 ? (j) : iB);                           \
    dA = c0 ? d0 : (c1 ? (d) : dA);                           \
    iA = c0 ? i0 : (c1 ? (j) : iA);                           \
    d0 = c0 ? (d) : d0;                                       \
    i0 = c0 ? (j) : i0;                                       \
} while (0)

#define SCAN(JS, JE) for (int j = (JS) + g; j < (JE); j += 8) {        \
    const f32x4 p = *(const f32x4*)&pp[j][0];                          \
    float fx = qx - p[0], fy = qy - p[1], fz = qz - p[2];              \
    float dd = fx*fx + fy*fy + fz*fz;                                  \
    INS(dd, j);                                                        \
}

#define MERGE8() do {                                                          \
    _Pragma("unroll")                                                          \
    for (int mm = 1; mm < 8; mm <<= 1) {                                       \
        float e0 = __shfl_xor(d0, mm), e1 = __shfl_xor(dA, mm), e2 = __shfl_xor(dB, mm); \
        int   f0 = __shfl_xor(i0, mm), f1 = __shfl_xor(iA, mm), f2 = __shfl_xor(iB, mm); \
        INS(e0, f0); INS(e1, f1); INS(e2, f2);                                 \
    }                                                                          \
} while (0)

__global__ __launch_bounds__(256)
void knn_grid_kernel(const float* __restrict__ pos_skip,
                     const float* __restrict__ gp,
                     const int* __restrict__ gcs,
                     int* __restrict__ widx, float* __restrict__ wval)
{
    __shared__ __align__(16) float pp[NC][4];       // 16KB: xyz + orig idx
    __shared__ unsigned short cs[513];
    const int bpc = NF/KQPB;              // 128 blocks per cloud
    const int b  = blockIdx.x / bpc;
    const int qb = blockIdx.x % bpc;
    const int t  = threadIdx.x;
    for (int i = t; i < NC; i += 256)
        *(f32x4*)&pp[i][0] = *(const f32x4*)&gp[(size_t)(b*NC + i)*4];
    for (int i = t; i < 513; i += 256) cs[i] = (unsigned short)gcs[b*513 + i];
    __syncthreads();

    const int g  = t & 7;
    const int ql = t >> 3;
    const int q  = b*NF + qb*KQPB + ql;
    const float qx = pos_skip[(size_t)q*3+0];
    const float qy = pos_skip[(size_t)q*3+1];
    const float qz = pos_skip[(size_t)q*3+2];
    const int cx = min(7, (int)(qx*8.0f));
    const int cy = min(7, (int)(qy*8.0f));
    const int cz = min(7, (int)(qz*8.0f));

    float d0 = 3.0e38f, dA = 3.0e38f, dB = 3.0e38f;
    int   i0 = 0,       iA = 0,       iB = 0;

    // ---- ring 1: 3x3x3 clamped; 9 (z,y) rows, fused x-span; lanes stride 8 ----
    const int xlo = max(cx-1,0), xhi = min(cx+1,7);
    const int ylo = max(cy-1,0), yhi = min(cy+1,7);
    const int zlo = max(cz-1,0), zhi = min(cz+1,7);
    #pragma unroll
    for (int r = 0; r < 9; ++r) {
        const int z = cz - 1 + r/3;
        const int y = cy - 1 + r%3;
        const bool ok = ((unsigned)z < 8u) & ((unsigned)y < 8u);
        const int rb = (z*8 + y)*8;
        int js = 0, je = 0;
        if (ok) { js = cs[rb + xlo]; je = cs[rb + xhi + 1]; }
        SCAN(js, je);
    }
    MERGE8();   // all 8 lanes hold identical exact top-3

    // ---- exactness margin of scanned box (domain edges = INF) ----
    float m1 = 3.0e38f;
    if (xlo > 0) m1 = fminf(m1, qx - xlo*0.125f);
    if (xhi < 7) m1 = fminf(m1, (xhi+1)*0.125f - qx);
    if (ylo > 0) m1 = fminf(m1, qy - ylo*0.125f);
    if (yhi < 7) m1 = fminf(m1, (yhi+1)*0.125f - qy);
    if (zlo > 0) m1 = fminf(m1, qz - zlo*0.125f);
    if (zhi < 7) m1 = fminf(m1, (zhi+1)*0.125f - qz);

    if (dB > m1*m1) {   // ~1-2% of queries; group-uniform
        const float s0 = d0, s1 = dA, s2 = dB;
        const int   t0 = i0, t1 = iA, t2 = iB;
        d0 = dA = dB = 3.0e38f; i0 = iA = iB = 0;

        const int xlo2 = max(cx-2,0), xhi2 = min(cx+2,7);
        const int ylo2 = max(cy-2,0), yhi2 = min(cy+2,7);
        const int zlo2 = max(cz-2,0), zhi2 = min(cz+2,7);
        for (int z = zlo2; z <= zhi2; ++z)
        for (int y = ylo2; y <= yhi2; ++y) {
            const int rb = (z*8 + y)*8;
            const bool inner_zy = (z >= zlo && z <= zhi && y >= ylo && y <= yhi);
            int jsA, jeA, jsB, jeB;
            if (inner_zy) {   // only unscanned x-edges (disjoint from ring 1)
                jsA = cs[rb + xlo2]; jeA = cs[rb + xlo];
                jsB = cs[rb + xhi + 1]; jeB = cs[rb + xhi2 + 1];
            } else {
                jsA = cs[rb + xlo2]; jeA = cs[rb + xhi2 + 1];
                jsB = 0; jeB = 0;
            }
            SCAN(jsA, jeA);
            SCAN(jsB, jeB);
        }
        MERGE8();
        INS(s0, t0); INS(s1, t1); INS(s2, t2);   // merge saved ring-1 triple

        float m2 = 3.0e38f;
        if (xlo2 > 0) m2 = fminf(m2, qx - xlo2*0.125f);
        if (xhi2 < 7) m2 = fminf(m2, (xhi2+1)*0.125f - qx);
        if (ylo2 > 0) m2 = fminf(m2, qy - ylo2*0.125f);
        if (yhi2 < 7) m2 = fminf(m2, (yhi2+1)*0.125f - qy);
        if (zlo2 > 0) m2 = fminf(m2, qz - zlo2*0.125f);
        if (zhi2 < 7) m2 = fminf(m2, (zhi2+1)*0.125f - qz);
        if (dB > m2*m2) {   // astronomically rare; guarantees exactness
            const float u0 = d0, u1 = dA, u2 = dB;
            const int   v0 = i0, v1 = iA, v2 = iB;
            d0 = dA = dB = 3.0e38f; i0 = iA = iB = 0;
            for (int j = g; j < NC; j += 8) {
                const f32x4 p = *(const f32x4*)&pp[j][0];
                int pcx = min(7, (int)(p[0]*8.0f));
                int pcy = min(7, (int)(p[1]*8.0f));
                int pcz = min(7, (int)(p[2]*8.0f));
                if (pcx >= xlo2 && pcx <= xhi2 && pcy >= ylo2 && pcy <= yhi2 &&
                    pcz >= zlo2 && pcz <= zhi2) continue;   // already scanned
                float fx = qx - p[0], fy = qy - p[1], fz = qz - p[2];
                float dd = fx*fx + fy*fy + fz*fz;
                INS(dd, j);
            }
            MERGE8();
            INS(u0, v0); INS(u1, v1); INS(u2, v2);
        }
    }

    if (g == 0) {
        const int o0 = __float_as_int(pp[i0][3]);
        const int o1 = __float_as_int(pp[iA][3]);
        const int o2 = __float_as_int(pp[iB][3]);
        float w0 = 1.0f / fmaxf(d0, 1e-16f);
        float w1 = 1.0f / fmaxf(dA, 1e-16f);
        float w2 = 1.0f / fmaxf(dB, 1e-16f);
        float inv = 1.0f / (w0 + w1 + w2);
        widx[q*3+0] = b*NC + o0;  wval[q*3+0] = w0*inv;
        widx[q*3+1] = b*NC + o1;  wval[q*3+1] = w1*inv;
        widx[q*3+2] = b*NC + o2;  wval[q*3+2] = w2*inv;
    }
}

// ---------------- K2: weights -> bf16, transposed [N][K] ----------------
__global__ __launch_bounds__(256)
void prep_weights(const float* __restrict__ W1, const float* __restrict__ W2,
                  __hip_bfloat16* __restrict__ W1t, __hip_bfloat16* __restrict__ W2t)
{
    int e = blockIdx.x*256 + threadIdx.x;
    if (e < CMID*KH) {
        int n = e / KH, k = e % KH;
        W1t[e] = __float2bfloat16(W1[(size_t)k*CMID + n]);
    }
    int e2 = e - CMID*KH;
    if (e2 >= 0 && e2 < COUT*CMID) {
        int n = e2 / CMID, k = e2 % CMID;
        W2t[e2] = __float2bfloat16(W2[(size_t)k*COUT + n]);
    }
}

// ---------------- fused MLP: interp+concat -> GEMM1(relu) in LDS -> GEMM2(relu) ----------------
// BM=64, BN=256, BK=64; 8 waves (2x4), wave tile 32x64.
__global__ __launch_bounds__(512, 4)
void mlp_fused(const float* __restrict__ x,
               const float* __restrict__ x_skip,
               const int* __restrict__ widx,
               const float* __restrict__ wval,
               const __hip_bfloat16* __restrict__ W1t,   // [CMID][KH]
               const float* __restrict__ b1,
               const __hip_bfloat16* __restrict__ W2t,   // [COUT][CMID]
               const float* __restrict__ b2,
               float* __restrict__ out)
{
    __shared__ __align__(16) short As[64][64];     //  8KB
    __shared__ __align__(16) short Bs[256][64];    // 32KB
    __shared__ __align__(16) short Hs[64][256];    // 32KB
    const int nwg = gridDim.x;                     // 1024 (%8==0)
    const int tile = (blockIdx.x & 7)*(nwg >> 3) + (blockIdx.x >> 3);
    const int m0 = tile * 64;

    const int t = threadIdx.x;
    const int wave = t >> 6, lane = t & 63;
    const int wm = wave >> 2, wn = wave & 3;       // 2x4 wave grid
    const int rl = lane & 15, kq = lane >> 4;
    const short* B1r = (const short*)W1t;
    const short* B2r = (const short*)W2t;

    const int ar = t >> 3;        // A-staging row 0..63
    const int ac = t & 7;         // A chunk 0..7

    const int gr = m0 + ar;
    const int j0 = widx[gr*3+0], j1 = widx[gr*3+1], j2 = widx[gr*3+2];
    const float w0 = wval[gr*3+0], w1 = wval[gr*3+1], w2 = wval[gr*3+2];

    f32x4 rA[6];
    u32x4 rB[4];

    #define LOADB(BP, KT, K0) do {                                             \
        _Pragma("unroll")                                                      \
        for (int i = 0; i < 4; ++i) {                                          \
            const int ch = t + i*512;                                          \
            const int rr = ch >> 3, cc = ch & 7;                               \
            rB[i] = *(const u32x4*)&(BP)[(size_t)rr*(KT) + (K0) + cc*8];       \
        }                                                                      \
    } while (0)

    #define LOADA1(K0) do {                                                   \
        if ((K0) < CIN) {                                                      \
            const int k = (K0) + ac*8;                                         \
            const float* p0 = &x[(size_t)j0*CIN + k];                          \
            const float* p1 = &x[(size_t)j1*CIN + k];                          \
            const float* p2 = &x[(size_t)j2*CIN + k];                          \
            rA[0] = *(const f32x4*)p0; rA[1] = *(const f32x4*)(p0+4);          \
            rA[2] = *(const f32x4*)p1; rA[3] = *(const f32x4*)(p1+4);          \
            rA[4] = *(const f32x4*)p2; rA[5] = *(const f32x4*)(p2+4);          \
        } else {                                                               \
            const int k = (K0) + ac*8 - CIN;                                   \
            const float* sp = &x_skip[(size_t)gr*CSKIP + k];                   \
            rA[0] = *(const f32x4*)sp; rA[1] = *(const f32x4*)(sp+4);          \
        }                                                                      \
    } while (0)

    f32x4 acc[2][4] = {};

    LOADA1(0); LOADB(B1r, KH, 0);

    // ---------------- phase 1: K = 384, 6 steps ----------------
    #pragma unroll
    for (int s = 0; s < 6; ++s) {
        const int k0 = s * 64;
        __syncthreads();
        {
            short8 sv;
            if (k0 < CIN) {
                #pragma unroll
                for (int u = 0; u < 2; ++u) {
                    f32x4 a = rA[u], bq = rA[2+u], c = rA[4+u];
                    #pragma unroll
                    for (int e = 0; e < 4; ++e) {
                        float v = w0*a[e] + w1*bq[e] + w2*c[e];
                        __hip_bfloat16 bb = __float2bfloat16(v);
                        ((short*)&sv)[u*4+e] = *(short*)&bb;
                    }
                }
            } else {
                #pragma unroll
                for (int u = 0; u < 2; ++u) {
                    f32x4 a = rA[u];
                    #pragma unroll
                    for (int e = 0; e < 4; ++e) {
                        __hip_bfloat16 bb = __float2bfloat16(a[e]);
                        ((short*)&sv)[u*4+e] = *(short*)&bb;
                    }
                }
            }
            *(short8*)&As[ar][(ac ^ (ar&7))*8] = sv;
        }
        #pragma unroll
        for (int i = 0; i < 4; ++i) {
            const int ch = t + i*512;
            const int rr = ch >> 3, cc = ch & 7;
            *(u32x4*)&Bs[rr][(cc ^ (rr&7))*8] = rB[i];
        }
        __syncthreads();
        if (s < 5) { LOADA1(k0 + 64); LOADB(B1r, KH, k0 + 64); }
        else       { LOADB(B2r, CMID, 0); }      // prefetch phase-2 step 0
        #pragma unroll
        for (int kh = 0; kh < 2; ++kh) {
            const int kc = kh*4 + kq;
            short8 af[2], bf[4];
            #pragma unroll
            for (int mf = 0; mf < 2; ++mf)
                af[mf] = *(const short8*)&As[wm*32 + mf*16 + rl][(kc ^ (rl&7))*8];
            #pragma unroll
            for (int nf = 0; nf < 4; ++nf)
                bf[nf] = *(const short8*)&Bs[wn*64 + nf*16 + rl][(kc ^ (rl&7))*8];
            #pragma unroll
            for (int mf = 0; mf < 2; ++mf)
            #pragma unroll
            for (int nf = 0; nf < 4; ++nf)
                acc[mf][nf] = __builtin_amdgcn_mfma_f32_16x16x32_bf16(af[mf], bf[nf], acc[mf][nf], 0,0,0);
        }
    }

    // ---------------- epilogue 1: relu+bias -> Hs (bf16, chunk-XOR swizzled) ----------------
    #pragma unroll
    for (int mf = 0; mf < 2; ++mf)
    #pragma unroll
    for (int nf = 0; nf < 4; ++nf) {
        const int col = wn*64 + nf*16 + rl;
        const float bv = b1[col];
        #pragma unroll
        for (int i = 0; i < 4; ++i) {
            const int row = wm*32 + mf*16 + kq*4 + i;
            float v = fmaxf(acc[mf][nf][i] + bv, 0.0f);
            __hip_bfloat16 bb = __float2bfloat16(v);
            Hs[row][((col >> 3) ^ (row & 7))*8 + (col & 7)] = *(short*)&bb;
        }
    }
    __syncthreads();   // Hs complete; all phase-1 Bs reads done

    // ---------------- phase 2: K = 256, 4 steps; A = Hs ----------------
    f32x4 acc2[2][4] = {};
    #pragma unroll
    for (int s = 0; s < 4; ++s) {
        if (s > 0) __syncthreads();
        #pragma unroll
        for (int i = 0; i < 4; ++i) {
            const int ch = t + i*512;
            const int rr = ch >> 3, cc = ch & 7;
            *(u32x4*)&Bs[rr][(cc ^ (rr&7))*8] = rB[i];
        }
        __syncthreads();
        if (s < 3) LOADB(B2r, CMID, (s+1)*64);
        #pragma unroll
        for (int kh = 0; kh < 2; ++kh) {
            const int kcl = kh*4 + kq;           // chunk within step
            const int kca = s*8 + kcl;           // absolute chunk in Hs
            short8 af[2], bf[4];
            #pragma unroll
            for (int mf = 0; mf < 2; ++mf)
                af[mf] = *(const short8*)&Hs[wm*32 + mf*16 + rl][(kca ^ (rl&7))*8];
            #pragma unroll
            for (int nf = 0; nf < 4; ++nf)
                bf[nf] = *(const short8*)&Bs[wn*64 + nf*16 + rl][(kcl ^ (rl&7))*8];
            #pragma unroll
            for (int mf = 0; mf < 2; ++mf)
            #pragma unroll
            for (int nf = 0; nf < 4; ++nf)
                acc2[mf][nf] = __builtin_amdgcn_mfma_f32_16x16x32_bf16(af[mf], bf[nf], acc2[mf][nf], 0,0,0);
        }
    }
    #undef LOADA1
    #undef LOADB

    // ---------------- epilogue 2: relu+bias -> out f32 ----------------
    #pragma unroll
    for (int mf = 0; mf < 2; ++mf)
    #pragma unroll
    for (int nf = 0; nf < 4; ++nf) {
        const int col = wn*64 + nf*16 + rl;
        const float bv = b2[col];
        #pragma unroll
        for (int i = 0; i < 4; ++i) {
            const int row = m0 + wm*32 + mf*16 + kq*4 + i;
            out[(size_t)row*COUT + col] = fmaxf(acc2[mf][nf][i] + bv, 0.0f);
        }
    }
}

// ---------------- K6: pos_skip + batch chunks ----------------
__global__ __launch_bounds__(256)
void tail_kernel(const float* __restrict__ pos_skip, float* __restrict__ out)
{
    int e = blockIdx.x*256 + threadIdx.x;
    if (e < NFINE*3) out[(size_t)NFINE*COUT + e] = pos_skip[e];
    if (e < NFINE)   out[(size_t)NFINE*COUT + (size_t)NFINE*3 + e] = (float)(e / NF);
}

extern "C" void kernel_launch(void* const* d_in, const int* in_sizes, int n_in,
                              void* d_out, int out_size, void* d_ws, size_t ws_size,
                              hipStream_t stream) {
    const float* x        = (const float*)d_in[0];
    const float* pos      = (const float*)d_in[1];
    const float* x_skip   = (const float*)d_in[4];
    const float* pos_skip = (const float*)d_in[5];
    const float* W1       = (const float*)d_in[8];
    const float* b1       = (const float*)d_in[9];
    const float* W2       = (const float*)d_in[10];
    const float* b2       = (const float*)d_in[11];
    float* out = (float*)d_out;
    char* ws = (char*)d_ws;

    int*            widx = (int*)  (ws + 0);                 //   786,432 B
    float*          wval = (float*)(ws + 786432);            //   786,432 B
    __hip_bfloat16* W1t  = (__hip_bfloat16*)(ws + 1572864);  //   196,608 B
    __hip_bfloat16* W2t  = (__hip_bfloat16*)(ws + 1769472);  //   131,072 B
    float*          gp   = (float*)(ws + 1900544);           //   262,144 B
    int*            gcs  = (int*)  (ws + 2162688);           //    32,832 B

    hipLaunchKernelGGL(bin_kernel, dim3(NB), dim3(256), 0, stream,
                       pos, gp, gcs);
    hipLaunchKernelGGL(knn_grid_kernel, dim3(NB*(NF/KQPB)), dim3(256), 0, stream,
                       pos_skip, gp, gcs, widx, wval);
    hipLaunchKernelGGL(prep_weights, dim3((CMID*KH + COUT*CMID + 255)/256), dim3(256), 0, stream,
                       W1, W2, W1t, W2t);
    hipLaunchKernelGGL(mlp_fused, dim3(NFINE/64), dim3(512), 0, stream,
                       x, x_skip, widx, wval, W1t, b1, W2t, b2, out);
    hipLaunchKernelGGL(tail_kernel, dim3((NFINE*3 + 255)/256), dim3(256), 0, stream,
                       pos_skip, out);
}